// Round 2
// baseline (127.202 us; speedup 1.0000x reference)
//
#include <hip/hip_runtime.h>
#include <math.h>

// Adder2D: out[n,co,h,w] = -sum_{ci,kh,kw} |x[n,ci,h+kh-1,w+kw-1] - w[co,ci,kh,kw]|
// x: [16,64,32,32] f32, w: [64,64,3,3] f32, out: [16,64,32,32] f32, pad=1 stride=1.
//
// R2 design: ALL-LDS inner loop. R1 mixed s_load(w) + ds_read(x) in the same
// lgkmcnt counter; SMEM is out-of-order vs DS, forcing conservative
// lgkmcnt(0) drains every ci iteration (VALUBusy 58%, 45us VALU issue vs
// 15.4us floor). Now w is staged once per block into LDS as ws[ci][tap][4co]
// (16B rows -> one ds_read_b128 broadcast per tap); inner loop is pure
// DS + VALU, so the compiler can issue fine-grained in-order lgkmcnt(N).

#define N_   16
#define CI_  64
#define CO_  64
#define HW_  32
#define K_   3
#define CG   4    // co per thread
#define RG   8    // output rows per block
#define CIC  8    // ci planes staged per barrier round

__global__ __launch_bounds__(256, 4) void adder2d_kernel(
    const float* __restrict__ x, const float* __restrict__ w,
    float* __restrict__ out)
{
    __shared__ __align__(16) float xs[CIC][RG + 2][HW_ + 2];  // 10880 B
    __shared__ __align__(16) float ws[CI_][9][CG];            // 9216 B: [ci][tap][co]

    const int tid = threadIdx.x;
    const int c   = tid & 31;        // output col
    const int rl  = tid >> 5;        // local row 0..7
    const int r0  = blockIdx.x * RG;
    const int co0 = blockIdx.y * CG;
    const int n   = blockIdx.z;
    const int r   = r0 + rl;

    // ---- stage w once: w[co0+j][ci][t] -> ws[ci][t][j] ----
    // global reads fully coalesced (contiguous per j); LDS write conflicts
    // (8-way) happen once per kernel -> negligible.
    for (int i = tid; i < CG * CI_ * 9; i += 256) {
        int j   = i / (CI_ * 9);
        int rem = i - j * (CI_ * 9);
        int ci  = rem / 9;
        int t   = rem - ci * 9;
        ws[ci][t][j] = w[(co0 + j) * CI_ * 9 + rem];
    }

    float acc[CG];
#pragma unroll
    for (int j = 0; j < CG; ++j) acc[j] = 0.f;

    const float* xn = x + (size_t)n * CI_ * HW_ * HW_;

    for (int cc0 = 0; cc0 < CI_; cc0 += CIC) {
        __syncthreads();   // protect LDS from previous round's readers (also covers w stage)
        // stage CIC padded planes: [CIC][RG+2][HW_+2], zeros in the halo OOB
        for (int idx = tid; idx < CIC * (RG + 2) * (HW_ + 2); idx += 256) {
            int cil = idx / ((RG + 2) * (HW_ + 2));
            int rem = idx - cil * ((RG + 2) * (HW_ + 2));
            int rr  = rem / (HW_ + 2);
            int cc  = rem - rr * (HW_ + 2);
            int gr  = r0 - 1 + rr;
            int gc  = cc - 1;
            float v = 0.f;
            if ((unsigned)gr < HW_ && (unsigned)gc < HW_)
                v = xn[(cc0 + cil) * HW_ * HW_ + gr * HW_ + gc];
            ((float*)xs)[idx] = v;
        }
        __syncthreads();

#pragma unroll 2
        for (int cil = 0; cil < CIC; ++cil) {
            const int ci = cc0 + cil;

            // 9 ds_read_b128 broadcasts: wv[t] = w[co0..co0+3][ci][t]
            float4 wv[9];
#pragma unroll
            for (int t = 0; t < 9; ++t)
                wv[t] = *(const float4*)&ws[ci][t][0];

            // 9 ds_read_b32 for this pixel's 3x3 patch (2-way alias = free)
            float xv[9];
#pragma unroll
            for (int kh = 0; kh < K_; ++kh)
#pragma unroll
                for (int kw = 0; kw < K_; ++kw)
                    xv[kh * 3 + kw] = xs[cil][rl + kh][c + kw];

            // 72 VALU: v_sub + v_add with |.| source modifier
#pragma unroll
            for (int t = 0; t < 9; ++t) {
                acc[0] += fabsf(xv[t] - wv[t].x);
                acc[1] += fabsf(xv[t] - wv[t].y);
                acc[2] += fabsf(xv[t] - wv[t].z);
                acc[3] += fabsf(xv[t] - wv[t].w);
            }
        }
    }

    float* on = out + ((size_t)n * CO_ + co0) * HW_ * HW_ + r * HW_ + c;
#pragma unroll
    for (int j = 0; j < CG; ++j)
        on[j * HW_ * HW_] = -acc[j];
}

extern "C" void kernel_launch(void* const* d_in, const int* in_sizes, int n_in,
                              void* d_out, int out_size, void* d_ws, size_t ws_size,
                              hipStream_t stream) {
    const float* x  = (const float*)d_in[0];
    const float* wp = (const float*)d_in[1];
    float* out      = (float*)d_out;
    dim3 grid(HW_ / RG, CO_ / CG, N_);   // (4, 16, 16) = 1024 blocks
    adder2d_kernel<<<grid, 256, 0, stream>>>(x, wp, out);
}

// Round 3
// 106.542 us; speedup vs baseline: 1.1939x; 1.1939x over previous
//
#include <hip/hip_runtime.h>
#include <math.h>

// Adder2D: out[n,co,h,w] = -sum_{ci,kh,kw} |x[n,ci,h+kh-1,w+kw-1] - w[co,ci,kh,kw]|
// x: [16,64,32,32] f32, w: [64,64,3,3] f32, out: [16,64,32,32] f32, pad=1 stride=1.
//
// R3: raise elem-ops per instruction. R1/R2 both ~80us with VALUBusy ~60%
// (~48us VALU issue vs 15.4us compute floor): excess instruction count in
// staging index math + per-ci overhead, amortized over only 36 elem-ops.
// Now: thread = 2 adjacent pixels x 4 co (144 VALU per ~15 LDS insts/ci),
// unpadded 32-col LDS rows (aligned float4 staging, cheap index math),
// col-halo via cndmask in-loop, row-halo via one-time zeroed edge slots.
// Block = 8 co x (8 rows x 32 cols) = 2048 outputs; grid 512 = 2 blocks/CU.

#define N_   16
#define CI_  64
#define CO_  64
#define HW_  32
#define CG   4     // co per thread
#define COB  8     // co per block
#define RG   8     // pixel rows per block
#define CIC  16    // ci planes per round
#define ROWS (RG + 2)

__global__ __launch_bounds__(256, 2) void adder2d_kernel(
    const float* __restrict__ x, const float* __restrict__ w,
    float* __restrict__ out)
{
    __shared__ __align__(16) float xs[CIC][ROWS][HW_];   // 16*10*32*4 = 20480 B
    __shared__ __align__(16) float ws[CI_][9][COB];      // 64*9*8*4  = 18432 B

    const int tid   = threadIdx.x;
    const int u     = tid & 15;          // col-pair: pixels at cols 2u, 2u+1
    const int rl    = (tid >> 4) & 7;    // pixel row within block
    const int cosub = tid >> 7;          // 0..1: co half
    const int r0    = blockIdx.x * RG;
    const int co0   = blockIdx.y * COB;
    const int n     = blockIdx.z;

    // ---- stage w once: w[co0+cl][ci][t] -> ws[ci][t][cl]  (18 iters) ----
    for (int i = tid; i < COB * CI_ * 9; i += 256) {
        int cl  = i / (CI_ * 9);
        int rem = i - cl * (CI_ * 9);    // = ci*9 + t
        ws[rem / 9][rem % 9][cl] = w[(co0 + cl) * (CI_ * 9) + rem];
    }
    // ---- zero the two halo row slots once (staging only writes in-bounds
    //      rows, so OOB slots stay zero; in-bounds slots get overwritten) ----
    {
        int p = tid >> 4;                // plane 0..15
        int s = (tid >> 3) & 1;          // 0 -> slot 0, 1 -> slot ROWS-1
        int f = tid & 7;                 // float4 index in row
        ((float4*)&xs[p][s ? (ROWS - 1) : 0][0])[f] = float4{0.f, 0.f, 0.f, 0.f};
    }

    float acc0[CG], acc1[CG];
#pragma unroll
    for (int j = 0; j < CG; ++j) { acc0[j] = 0.f; acc1[j] = 0.f; }

    const float* xn = x + (size_t)n * CI_ * HW_ * HW_;

    const bool has_l = (u != 0);
    const bool has_r = (u != 15);
    const int  col_l = has_l ? (2 * u - 1) : 0;        // clamped (masked below)
    const int  col_r = has_r ? (2 * u + 2) : (HW_ - 1);

    for (int round = 0; round < CI_ / CIC; ++round) {
        const int cc0 = round * CIC;
        __syncthreads();   // protect LDS from previous round's readers
        // ---- stage CIC planes, rows r0-1..r0+8, aligned float4 (5 iters) ----
        for (int i = tid; i < CIC * ROWS * (HW_ / 4); i += 256) {
            int plane = i / (ROWS * (HW_ / 4));
            int rem   = i - plane * (ROWS * (HW_ / 4));
            int rr    = rem >> 3;
            int f4    = rem & 7;
            int gr    = r0 - 1 + rr;
            if ((unsigned)gr < HW_)
                ((float4*)&xs[plane][rr][0])[f4] =
                    ((const float4*)(xn + (size_t)(cc0 + plane) * HW_ * HW_ + gr * HW_))[f4];
        }
        __syncthreads();

#pragma unroll 4
        for (int cil = 0; cil < CIC; ++cil) {
            const int ci = cc0 + cil;

            // 9 b128 broadcasts: wv[t][j] = w[co0+4*cosub+j][ci][t]
            float4 wv[9];
#pragma unroll
            for (int t = 0; t < 9; ++t)
                wv[t] = *(const float4*)&ws[ci][t][cosub * CG];

            // x patch for 2 pixels: rows rl..rl+2, cols 2u-1..2u+2
            float2 xm[3]; float xl[3], xr[3];
#pragma unroll
            for (int kh = 0; kh < 3; ++kh) {
                const float* row = &xs[cil][rl + kh][0];
                xm[kh] = *(const float2*)&row[2 * u];
                float tl = row[col_l];
                float tr = row[col_r];
                xl[kh] = has_l ? tl : 0.f;   // zero-pad left edge
                xr[kh] = has_r ? tr : 0.f;   // zero-pad right edge
            }

            // 144 VALU: 2 pix x 4 co x 9 taps, sub + add-with-|.|-modifier
#pragma unroll
            for (int kh = 0; kh < 3; ++kh)
#pragma unroll
                for (int kw = 0; kw < 3; ++kw) {
                    const int t = kh * 3 + kw;
                    float xa = (kw == 0) ? xl[kh] : ((kw == 1) ? xm[kh].x : xm[kh].y);
                    float xb = (kw == 0) ? xm[kh].x : ((kw == 1) ? xm[kh].y : xr[kh]);
                    const float* wj = (const float*)&wv[t];
#pragma unroll
                    for (int j = 0; j < CG; ++j) {
                        acc0[j] += fabsf(xa - wj[j]);
                        acc1[j] += fabsf(xb - wj[j]);
                    }
                }
        }
    }

    float* op = out + (((size_t)n * CO_ + co0 + cosub * CG) * HW_ + (r0 + rl)) * HW_ + 2 * u;
#pragma unroll
    for (int j = 0; j < CG; ++j)
        *(float2*)&op[(size_t)j * HW_ * HW_] = float2{-acc0[j], -acc1[j]};
}

extern "C" void kernel_launch(void* const* d_in, const int* in_sizes, int n_in,
                              void* d_out, int out_size, void* d_ws, size_t ws_size,
                              hipStream_t stream) {
    const float* x  = (const float*)d_in[0];
    const float* wp = (const float*)d_in[1];
    float* out      = (float*)d_out;
    dim3 grid(HW_ / RG, CO_ / COB, N_);   // (4, 8, 16) = 512 blocks
    adder2d_kernel<<<grid, 256, 0, stream>>>(x, wp, out);
}